// Round 2
// baseline (580.127 us; speedup 1.0000x reference)
//
#include <hip/hip_runtime.h>

#define Bz  32
#define NQz 1024
#define NKz 1024
#define SCALE 0.04419417382415922f  // 1/sqrt(512)

typedef __bf16 bf16_t;
typedef bf16_t bf16x8 __attribute__((ext_vector_type(8)));
typedef bf16_t bf16x4 __attribute__((ext_vector_type(4)));
typedef float  f32x4  __attribute__((ext_vector_type(4)));

#define MFMA16(a, b, c) __builtin_amdgcn_mfma_f32_16x16x32_bf16(a, b, c, 0, 0, 0)

// raw barrier + counted waitcnt (T3/T4 pattern): loads stay in flight across barriers
#define SBAR() asm volatile("s_barrier" ::: "memory")
#define WAITVM(n) asm volatile("s_waitcnt vmcnt(" #n ")" ::: "memory")
#define WAITVL(n) asm volatile("s_waitcnt vmcnt(" #n ") lgkmcnt(0)" ::: "memory")

// async global->LDS DMA, 16B per lane; LDS dest = lptr + lane*16 (wave-uniform base)
__device__ __forceinline__ void gll16(const void* g, void* l) {
  __builtin_amdgcn_global_load_lds(
      (const __attribute__((address_space(1))) void*)g,
      (__attribute__((address_space(3))) void*)l, 16, 0, 0);
}

// native exp2 (K pre-scaled by log2e, so exp(s) == exp2(s'))
__device__ __forceinline__ float fexp2(float x) {
#if __has_builtin(__builtin_amdgcn_exp2f)
  return __builtin_amdgcn_exp2f(x);
#else
  float r;
  asm("v_exp_f32 %0, %1" : "=v"(r) : "v"(x));
  return r;
#endif
}

__device__ __forceinline__ bf16x8 cvt8(float4 a, float4 b) {
  bf16x8 r;
  r[0] = (bf16_t)a.x; r[1] = (bf16_t)a.y; r[2] = (bf16_t)a.z; r[3] = (bf16_t)a.w;
  r[4] = (bf16_t)b.x; r[5] = (bf16_t)b.y; r[6] = (bf16_t)b.z; r[7] = (bf16_t)b.w;
  return r;
}

// ---- transpose + bf16-convert the four 512x512 weight matrices: Wt[n][k] = W[k][n]
__global__ void transpose_w(const float* __restrict__ W0, const float* __restrict__ W1,
                            const float* __restrict__ W2, const float* __restrict__ W3,
                            bf16_t* __restrict__ out) {
  __shared__ float tile[32][33];
  const float* W = blockIdx.z == 0 ? W0 : blockIdx.z == 1 ? W1 : blockIdx.z == 2 ? W2 : W3;
  bf16_t* o = out + (size_t)blockIdx.z * 512 * 512;
  const int n0 = blockIdx.x * 32, k0 = blockIdx.y * 32;
  const int tx = threadIdx.x, ty = threadIdx.y;  // (32,8)
  for (int i = 0; i < 4; i++)
    tile[ty + i * 8][tx] = W[(size_t)(k0 + ty + i * 8) * 512 + n0 + tx];
  __syncthreads();
  for (int i = 0; i < 4; i++)
    o[(size_t)(n0 + ty + i * 8) * 512 + k0 + tx] = (bf16_t)tile[tx][ty + i * 8];
}

// ===================== projection GEMMs (A = fp32 input) =====================
// 128x128 tile, double-buffered W staging (DMA, counted vmcnt) + A-register
// prefetch; 2 barriers/iter, vmcnt never drains to 0 in the main loop.
// Block index remapped so the NT n-tiles sharing an A-panel dispatch
// ADJACENTLY (A-panel stays hot in L2/L3 instead of 4-8x HBM refetch).
// DUAL=0: C0 = bf16((A@W + b0) * mult0), grid.y=4.
// DUAL=1: W spans [1024][512] (Wk||Wv); n0<512 -> C0 (bias b0, mult0),
//         else C1 (bias b1, mult 1). grid.y=8.
template <int DUAL>
__global__ __launch_bounds__(256) void gemm_f32a(const float* __restrict__ A,
                                                 const bf16_t* __restrict__ Wt,
                                                 const float* __restrict__ b0v,
                                                 const float* __restrict__ b1v,
                                                 float mult0,
                                                 bf16_t* __restrict__ C0,
                                                 bf16_t* __restrict__ C1) {
  __shared__ __align__(16) bf16_t As[128][40];
  __shared__ __align__(16) bf16_t Bs[2][128 * 32];
  const int t = threadIdx.x;
  const int wave = t >> 6, lane = t & 63;
  const int quad = lane >> 4, l16 = lane & 15;
  const int wm = wave & 1, wn = wave >> 1;
  const int flat = blockIdx.y * gridDim.x + blockIdx.x;
  const int m0 = (DUAL ? (flat >> 3) : (flat >> 2)) * 128;
  const int n0 = (DUAL ? (flat & 7) : (flat & 3)) * 128;
  const int r = t >> 1, half = t & 1;
  // DMA mapping: pass p -> row p*64 + wave*16 + (lane>>2), src granule (lane&3)^((lane>>3)&3)
  const int drow = lane >> 2;
  const int dg = (lane & 3) ^ ((lane >> 3) & 3);

  f32x4 acc[4][4] = {};

  const float* arow = A + (size_t)(m0 + r) * 512 + half * 16;
  const bf16_t* wrow = Wt + (size_t)(n0 + wave * 16 + drow) * 512 + dg * 8;

  // prologue: tile 0 in flight + A(0) regs
  for (int p = 0; p < 2; p++)
    gll16(wrow + (size_t)(p * 64) * 512, &Bs[0][(p * 256 + wave * 64) * 8]);
  float4 a0 = *(const float4*)(arow + 0);
  float4 a1 = *(const float4*)(arow + 4);
  float4 a2 = *(const float4*)(arow + 8);
  float4 a3 = *(const float4*)(arow + 12);

  for (int it = 0; it < 16; it++) {
    const int cur = it & 1;
    if (it < 15)
      for (int p = 0; p < 2; p++)
        gll16(wrow + (it + 1) * 32 + (size_t)(p * 64) * 512,
              &Bs[cur ^ 1][(p * 256 + wave * 64) * 8]);
    *(bf16x8*)&As[r][half * 16 + 0] = cvt8(a0, a1);
    *(bf16x8*)&As[r][half * 16 + 8] = cvt8(a2, a3);
    if (it < 15) {
      const float* ap = arow + (it + 1) * 32;
      a0 = *(const float4*)(ap + 0);
      a1 = *(const float4*)(ap + 4);
      a2 = *(const float4*)(ap + 8);
      a3 = *(const float4*)(ap + 12);
      WAITVL(6);  // 2 gll16(it+1) + 4 A loads newer; tile it done, As drained
    } else {
      WAITVL(0);
    }
    SBAR();
    bf16x8 af[4], bfv[4];
    for (int mt = 0; mt < 4; mt++)
      af[mt] = *(const bf16x8*)&As[wm * 64 + mt * 16 + l16][quad * 8];
    for (int nt = 0; nt < 4; nt++) {
      const int rB = wn * 64 + nt * 16 + l16;
      bfv[nt] = *(const bf16x8*)&Bs[cur][rB * 32 + ((quad ^ ((rB >> 1) & 3)) * 8)];
    }
    for (int mt = 0; mt < 4; mt++)
      for (int nt = 0; nt < 4; nt++)
        acc[mt][nt] = MFMA16(af[mt], bfv[nt], acc[mt][nt]);
    SBAR();  // all waves done reading As/Bs[cur] before next-iter restage
  }

  const float* bias = (!DUAL || n0 < 512) ? b0v : b1v;
  bf16_t* C = (!DUAL || n0 < 512) ? C0 : C1;
  const float mult = (!DUAL || n0 < 512) ? mult0 : 1.0f;
  const int nb = (!DUAL || n0 < 512) ? n0 : n0 - 512;
  for (int mt = 0; mt < 4; mt++) {
    for (int nt = 0; nt < 4; nt++) {
      const int row = m0 + wm * 64 + mt * 16 + quad * 4;
      const int col = nb + wn * 64 + nt * 16 + l16;
      const float bv = bias[col];
      for (int rg = 0; rg < 4; rg++)
        C[(size_t)(row + rg) * 512 + col] = (bf16_t)((acc[mt][nt][rg] + bv) * mult);
    }
  }
}

// ===================== output GEMM (A = bf16, resid+relu epilogue) ===========
__global__ __launch_bounds__(256) void gemm_bf16a(const bf16_t* __restrict__ A,
                                                  const bf16_t* __restrict__ Wt,
                                                  const float* __restrict__ bias,
                                                  bf16_t* __restrict__ C) {
  __shared__ __align__(16) bf16_t As[128][40];
  __shared__ __align__(16) bf16_t Bs[2][128 * 32];
  const int t = threadIdx.x;
  const int wave = t >> 6, lane = t & 63;
  const int quad = lane >> 4, l16 = lane & 15;
  const int wm = wave & 1, wn = wave >> 1;
  const int flat = blockIdx.y * gridDim.x + blockIdx.x;
  const int m0 = (flat >> 2) * 128, n0 = (flat & 3) * 128;
  const int r = t >> 1, half = t & 1;
  const int drow = lane >> 2;
  const int dg = (lane & 3) ^ ((lane >> 3) & 3);

  f32x4 acc[4][4] = {};

  const bf16_t* arow = A + (size_t)(m0 + r) * 512 + half * 16;
  const bf16_t* wrow = Wt + (size_t)(n0 + wave * 16 + drow) * 512 + dg * 8;

  for (int p = 0; p < 2; p++)
    gll16(wrow + (size_t)(p * 64) * 512, &Bs[0][(p * 256 + wave * 64) * 8]);
  bf16x8 v0 = *(const bf16x8*)(arow + 0);
  bf16x8 v1 = *(const bf16x8*)(arow + 8);

  for (int it = 0; it < 16; it++) {
    const int cur = it & 1;
    if (it < 15)
      for (int p = 0; p < 2; p++)
        gll16(wrow + (it + 1) * 32 + (size_t)(p * 64) * 512,
              &Bs[cur ^ 1][(p * 256 + wave * 64) * 8]);
    *(bf16x8*)&As[r][half * 16 + 0] = v0;
    *(bf16x8*)&As[r][half * 16 + 8] = v1;
    if (it < 15) {
      const bf16_t* ap = arow + (it + 1) * 32;
      v0 = *(const bf16x8*)(ap + 0);
      v1 = *(const bf16x8*)(ap + 8);
      WAITVL(4);  // 2 gll16(it+1) + 2 A loads newer; tile it done
    } else {
      WAITVL(0);
    }
    SBAR();
    bf16x8 af[4], bfv[4];
    for (int mt = 0; mt < 4; mt++)
      af[mt] = *(const bf16x8*)&As[wm * 64 + mt * 16 + l16][quad * 8];
    for (int nt = 0; nt < 4; nt++) {
      const int rB = wn * 64 + nt * 16 + l16;
      bfv[nt] = *(const bf16x8*)&Bs[cur][rB * 32 + ((quad ^ ((rB >> 1) & 3)) * 8)];
    }
    for (int mt = 0; mt < 4; mt++)
      for (int nt = 0; nt < 4; nt++)
        acc[mt][nt] = MFMA16(af[mt], bfv[nt], acc[mt][nt]);
    SBAR();
  }

  for (int mt = 0; mt < 4; mt++) {
    for (int nt = 0; nt < 4; nt++) {
      const int row = m0 + wm * 64 + mt * 16 + quad * 4;
      const int col = n0 + wn * 64 + nt * 16 + l16;
      const float bv = bias[col];
      for (int rg = 0; rg < 4; rg++) {
        float v = acc[mt][nt][rg] + bv;
        float x = (float)A[(size_t)(row + rg) * 512 + col];
        C[(size_t)(row + rg) * 512 + col] = (bf16_t)(x + fmaxf(v, 0.f));
      }
    }
  }
}

// ---- stats: l_k = sum_q exp(s[q,k]) (kp pre-scaled by SCALE*log2e -> exp2).
// Writes Vt[hb][d][k] = V[k][d]/l_k. Grid 2048 (XCD-swizzled). K A-frags in
// regs; Q tiles double-buffered DMA (XOR swizzle g^(row&7)), counted vmcnt.
// setprio(1) wraps the MFMA pairs (T5).
__global__ __launch_bounds__(256) void attn_stats(const bf16_t* __restrict__ qp,
                                                  const bf16_t* __restrict__ kp,
                                                  const bf16_t* __restrict__ vp,
                                                  bf16_t* __restrict__ Vt) {
  __shared__ __align__(16) bf16_t Vs[128][72];
  __shared__ __align__(16) bf16_t Qs[2][64 * 64];
  __shared__ float ls[128];
  const int t = threadIdx.x;
  const int wave = t >> 6, lane = t & 63;
  const int quad = lane >> 4, l16 = lane & 15;
  const int id = blockIdx.x;
  const int kb = ((id >> 3) & 7) * 128;
  const int hb = (id & 7) * 32 + (id >> 6);
  const int h = hb >> 5, b = hb & 31;
  const bf16_t* qbase = qp + (size_t)b * NQz * 512 + h * 64;
  const bf16_t* kbase = kp + (size_t)b * NKz * 512 + h * 64;
  // DMA mapping (8 granules/row): row p*32+wave*8+(lane>>3), src granule (lane&7)^(lane>>3)
  const int drow = lane >> 3;
  const int dg = (lane & 7) ^ drow;

  {  // stage V block for the epilogue transpose
    const int r = t >> 1, half = t & 1;
    const bf16_t* vr = vp + (size_t)b * NKz * 512 + (size_t)(kb + r) * 512 + h * 64 + half * 32;
    *(bf16x8*)&Vs[r][half * 32 + 0]  = *(const bf16x8*)(vr + 0);
    *(bf16x8*)&Vs[r][half * 32 + 8]  = *(const bf16x8*)(vr + 8);
    *(bf16x8*)&Vs[r][half * 32 + 16] = *(const bf16x8*)(vr + 16);
    *(bf16x8*)&Vs[r][half * 32 + 24] = *(const bf16x8*)(vr + 24);
  }

  bf16x8 aK[2][2];
  for (int mt = 0; mt < 2; mt++) {
    const bf16_t* kr = kbase + (size_t)(kb + wave * 32 + mt * 16 + l16) * 512 + quad * 8;
    aK[mt][0] = *(const bf16x8*)kr;
    aK[mt][1] = *(const bf16x8*)(kr + 32);
  }

  // prologue: q-tile 0 in flight
  for (int p = 0; p < 2; p++) {
    const bf16_t* src = qbase + (size_t)(p * 32 + wave * 8 + drow) * 512 + dg * 8;
    gll16(src, &Qs[0][(p * 256 + wave * 64) * 8]);
  }

  f32x4 lacc[2] = {};
  for (int it = 0; it < 16; it++) {
    const int cur = it & 1;
    if (it < 15) {
      const int qn = (it + 1) * 64;
      for (int p = 0; p < 2; p++) {
        const bf16_t* src = qbase + (size_t)(qn + p * 32 + wave * 8 + drow) * 512 + dg * 8;
        gll16(src, &Qs[cur ^ 1][(p * 256 + wave * 64) * 8]);
      }
      WAITVM(2);  // tile it done; tile it+1 (2 loads) stays in flight
    } else {
      WAITVM(0);
    }
    SBAR();
    for (int nt = 0; nt < 4; nt++) {
      const int rQ = nt * 16 + l16;
      bf16x8 b0 = *(const bf16x8*)&Qs[cur][rQ * 64 + ((quad ^ (rQ & 7)) * 8)];
      bf16x8 b1 = *(const bf16x8*)&Qs[cur][rQ * 64 + (((quad + 4) ^ (rQ & 7)) * 8)];
      for (int mt = 0; mt < 2; mt++) {
        f32x4 s = {0.f, 0.f, 0.f, 0.f};
        __builtin_amdgcn_s_setprio(1);
        s = MFMA16(aK[mt][0], b0, s);
        s = MFMA16(aK[mt][1], b1, s);
        __builtin_amdgcn_s_setprio(0);
        lacc[mt][0] += fexp2(s[0]);
        lacc[mt][1] += fexp2(s[1]);
        lacc[mt][2] += fexp2(s[2]);
        lacc[mt][3] += fexp2(s[3]);
      }
    }
    SBAR();  // all waves done reading Qs[cur] before restage
  }
  for (int mt = 0; mt < 2; mt++) {
    for (int rg = 0; rg < 4; rg++) {
      float v = lacc[mt][rg];
      v += __shfl_xor(v, 1);
      v += __shfl_xor(v, 2);
      v += __shfl_xor(v, 4);
      v += __shfl_xor(v, 8);
      if (l16 == 0) ls[wave * 32 + mt * 16 + quad * 4 + rg] = 1.0f / v;
    }
  }
  __syncthreads();
  const int d = t >> 2, kc = (t & 3) * 32;
  bf16_t* vtr = Vt + (size_t)hb * 64 * 1024 + (size_t)d * 1024 + kb + kc;
  for (int c = 0; c < 4; c++) {
    bf16x8 o;
    for (int j = 0; j < 8; j++)
      o[j] = (bf16_t)((float)Vs[kc + c * 8 + j][d] * ls[kc + c * 8 + j]);
    *(bf16x8*)(vtr + c * 8) = o;
  }
}

// ---- attn_out: O[q,d] = sum_k exp(s[q,k]) * Vt[d,k].  Grid 2048 (XCD-swizzled).
// K-tile double-buffered DMA (XOR swizzle, counted vmcnt); V B-frags read
// DIRECTLY from global (all waves share addresses -> L1; Vt slice L2-fits) --
// LDS 50->34.8KB = 4 blocks/CU. Q B-frags in regs; P via wave-private Ps rows.
// setprio(1) around MFMA clusters (T5).
__global__ __launch_bounds__(256, 4) void attn_out(const bf16_t* __restrict__ qp,
                                                   const bf16_t* __restrict__ kp,
                                                   const bf16_t* __restrict__ Vt,
                                                   bf16_t* __restrict__ oh) {
  __shared__ __align__(16) bf16_t Ks[2][64 * 64];
  __shared__ __align__(16) bf16_t Ps[128][72];
  const int t = threadIdx.x;
  const int wave = t >> 6, lane = t & 63;
  const int quad = lane >> 4, l16 = lane & 15;
  const int id = blockIdx.x;
  const int qt = (id >> 3) & 7;
  const int hb = (id & 7) * 32 + (id >> 6);
  const int h = hb >> 5, b = hb & 31;
  const int q0 = qt * 128;
  const bf16_t* qbase = qp + (size_t)b * NQz * 512 + h * 64;
  const bf16_t* kbase = kp + (size_t)b * NKz * 512 + h * 64;
  const bf16_t* vtbase = Vt + (size_t)hb * 64 * 1024;
  const int drow = lane >> 3;
  const int dg = (lane & 7) ^ drow;

  bf16x8 bQ[2][2];
  for (int nt = 0; nt < 2; nt++) {
    const bf16_t* qr = qbase + (size_t)(q0 + wave * 32 + nt * 16 + l16) * 512 + quad * 8;
    bQ[nt][0] = *(const bf16x8*)qr;
    bQ[nt][1] = *(const bf16x8*)(qr + 32);
  }
  // per-lane V row pointers (row = nd*16+l16 of Vt[d][k]), col base quad*8
  const bf16_t* vrow[4];
  for (int nd = 0; nd < 4; nd++)
    vrow[nd] = vtbase + (size_t)(nd * 16 + l16) * 1024 + quad * 8;

  // prologue: K tile 0 in flight
  for (int p = 0; p < 2; p++) {
    const bf16_t* ksrc = kbase + (size_t)(p * 32 + wave * 8 + drow) * 512 + dg * 8;
    gll16(ksrc, &Ks[0][(p * 256 + wave * 64) * 8]);
  }

  f32x4 acc[2][4] = {};
  for (int it = 0; it < 16; it++) {
    const int kk = it * 64;
    const int cur = it & 1;
    // V fragments for THIS tile, direct from global (issued before K staging
    // so the PV wait can leave the K prefetch in flight)
    bf16x8 vf[4][2];
    for (int nd = 0; nd < 4; nd++) {
      vf[nd][0] = *(const bf16x8*)(vrow[nd] + kk);
      vf[nd][1] = *(const bf16x8*)(vrow[nd] + kk + 32);
    }
    __builtin_amdgcn_sched_barrier(0);  // pin order: vf loads, THEN gll16
    if (it < 15) {
      const int kn = kk + 64;
      for (int p = 0; p < 2; p++) {
        const bf16_t* ksrc = kbase + (size_t)(kn + p * 32 + wave * 8 + drow) * 512 + dg * 8;
        gll16(ksrc, &Ks[cur ^ 1][(p * 256 + wave * 64) * 8]);
      }
      WAITVM(10);  // 8 vf + 2 gll16(next) newer; waits only tile-it K DMA
    } else {
      WAITVM(8);   // 8 vf newer; waits tile-15 K DMA
    }
    SBAR();
    // S^T: m = k (A-frag from Ks), n = q (regs). C rows = 4 consecutive k -> b64 pack.
    for (int mt = 0; mt < 4; mt++) {
      const int rK = mt * 16 + l16;
      bf16x8 a0 = *(const bf16x8*)&Ks[cur][rK * 64 + ((quad ^ (rK & 7)) * 8)];
      bf16x8 a1 = *(const bf16x8*)&Ks[cur][rK * 64 + (((quad + 4) ^ (rK & 7)) * 8)];
      for (int nt = 0; nt < 2; nt++) {
        f32x4 s = {0.f, 0.f, 0.f, 0.f};
        __builtin_amdgcn_s_setprio(1);
        s = MFMA16(a0, bQ[nt][0], s);
        s = MFMA16(a1, bQ[nt][1], s);
        __builtin_amdgcn_s_setprio(0);
        bf16x4 pk;
        pk[0] = (bf16_t)fexp2(s[0]);
        pk[1] = (bf16_t)fexp2(s[1]);
        pk[2] = (bf16_t)fexp2(s[2]);
        pk[3] = (bf16_t)fexp2(s[3]);
        *(bf16x4*)&Ps[wave * 32 + nt * 16 + l16][mt * 16 + quad * 4] = pk;
      }
    }
    // PV: A-frag = Ps rows (wave-private, b128), B-frag = vf regs.
    bf16x8 aP[2][2];
    for (int mt = 0; mt < 2; mt++) {
      aP[mt][0] = *(const bf16x8*)&Ps[wave * 32 + mt * 16 + l16][quad * 8];
      aP[mt][1] = *(const bf16x8*)&Ps[wave * 32 + mt * 16 + l16][quad * 8 + 32];
    }
    __builtin_amdgcn_s_setprio(1);
    for (int nd = 0; nd < 4; nd++) {
      for (int mt = 0; mt < 2; mt++) {
        acc[mt][nd] = MFMA16(aP[mt][0], vf[nd][0], acc[mt][nd]);
        acc[mt][nd] = MFMA16(aP[mt][1], vf[nd][1], acc[mt][nd]);
      }
    }
    __builtin_amdgcn_s_setprio(0);
    SBAR();  // all waves done reading Ks[cur] before next-iter restage
  }
  for (int mt = 0; mt < 2; mt++)
    for (int nd = 0; nd < 4; nd++)
      for (int rg = 0; rg < 4; rg++)
        Ps[wave * 32 + mt * 16 + quad * 4 + rg][nd * 16 + l16] = (bf16_t)acc[mt][nd][rg];
  const int row = wave * 32 + (lane >> 1), cc = (lane & 1) * 32;
  bf16_t* orow = oh + ((size_t)b * NQz + q0 + row) * 512 + h * 64 + cc;
  for (int c = 0; c < 4; c++)
    *(bf16x8*)(orow + c * 8) = *(const bf16x8*)&Ps[row][cc + c * 8];
}

// ---- LayerNorm over 512 cols, one wave per row, bf16 in.
template <int RES, int F32OUT>
__global__ __launch_bounds__(256) void ln_k(const bf16_t* __restrict__ x,
                                            const bf16_t* __restrict__ res,
                                            const float* __restrict__ g,
                                            const float* __restrict__ be,
                                            bf16_t* __restrict__ yb,
                                            float* __restrict__ yf) {
  const int wave = threadIdx.x >> 6, lane = threadIdx.x & 63;
  const size_t row = (size_t)blockIdx.x * 4 + wave;
  bf16x8 xv = *(const bf16x8*)(x + row * 512 + lane * 8);
  float xf[8];
  for (int i = 0; i < 8; i++) xf[i] = (float)xv[i];
  if (RES) {
    bf16x8 rv = *(const bf16x8*)(res + row * 512 + lane * 8);
    for (int i = 0; i < 8; i++) xf[i] += (float)rv[i];
  }
  float s = 0.f, sq = 0.f;
  for (int i = 0; i < 8; i++) { s += xf[i]; sq += xf[i] * xf[i]; }
  for (int off = 1; off < 64; off <<= 1) {
    s += __shfl_xor(s, off);
    sq += __shfl_xor(sq, off);
  }
  const float mu = s * (1.0f / 512.0f);
  const float var = sq * (1.0f / 512.0f) - mu * mu;
  const float rstd = rsqrtf(var + 1e-5f);
  float4 gv0 = *(const float4*)(g + lane * 8);
  float4 gv1 = *(const float4*)(g + lane * 8 + 4);
  float4 bv0 = *(const float4*)(be + lane * 8);
  float4 bv1 = *(const float4*)(be + lane * 8 + 4);
  float gg[8] = {gv0.x, gv0.y, gv0.z, gv0.w, gv1.x, gv1.y, gv1.z, gv1.w};
  float bb[8] = {bv0.x, bv0.y, bv0.z, bv0.w, bv1.x, bv1.y, bv1.z, bv1.w};
  float o[8];
  for (int i = 0; i < 8; i++) o[i] = (xf[i] - mu) * rstd * gg[i] + bb[i];
  if (F32OUT) {
    float4 o0 = {o[0], o[1], o[2], o[3]}, o1 = {o[4], o[5], o[6], o[7]};
    *(float4*)(yf + row * 512 + lane * 8) = o0;
    *(float4*)(yf + row * 512 + lane * 8 + 4) = o1;
  } else {
    bf16x8 ov;
    for (int i = 0; i < 8; i++) ov[i] = (bf16_t)o[i];
    *(bf16x8*)(yb + row * 512 + lane * 8) = ov;
  }
}

extern "C" void kernel_launch(void* const* d_in, const int* in_sizes, int n_in,
                              void* d_out, int out_size, void* d_ws, size_t ws_size,
                              hipStream_t stream) {
  (void)in_sizes; (void)n_in; (void)out_size; (void)ws_size;
  const float* Q   = (const float*)d_in[0];
  const float* K   = (const float*)d_in[1];
  const float* Wq  = (const float*)d_in[2];
  const float* bq  = (const float*)d_in[3];
  const float* Wk  = (const float*)d_in[4];
  const float* bk  = (const float*)d_in[5];
  const float* Wv  = (const float*)d_in[6];
  const float* bv  = (const float*)d_in[7];
  const float* Wo  = (const float*)d_in[8];
  const float* bo  = (const float*)d_in[9];
  const float* g0  = (const float*)d_in[10];
  const float* be0 = (const float*)d_in[11];
  const float* g1  = (const float*)d_in[12];
  const float* be1 = (const float*)d_in[13];
  float* outp = (float*)d_out;

  char* w = (char*)d_ws;
  bf16_t* Wt  = (bf16_t*)w;                     // 2 MB (4 x 512x512 bf16)
  bf16_t* qp  = (bf16_t*)(w + (2ull << 20));    // 32 MB (Q proj; residual source)
  bf16_t* kp  = (bf16_t*)(w + (34ull << 20));   // 32 MB (K proj, pre-scaled by SCALE*log2e)
  bf16_t* vp  = (bf16_t*)(w + (66ull << 20));   // 32 MB (V proj, dead after stats)
  bf16_t* Vt  = (bf16_t*)(w + (98ull << 20));   // 32 MB (V'/l transposed [hb][64][1024])
  bf16_t* ohb = (bf16_t*)(w + (130ull << 20));  // 32 MB (attn out, no resid)
  bf16_t* x0b = vp;                             // reuse: LN0 out
  bf16_t* oh2 = kp;                             // reuse: out-proj+relu+resid

  transpose_w<<<dim3(16, 16, 4), dim3(32, 8), 0, stream>>>(Wq, Wk, Wv, Wo, Wt);
  gemm_f32a<0><<<dim3(256, 4), 256, 0, stream>>>(Q, Wt, bq, nullptr, 1.0f, qp, nullptr);
  // fold log2(e) into K so attn kernels use native v_exp_f32 (exp2)
  gemm_f32a<1><<<dim3(256, 8), 256, 0, stream>>>(K, Wt + (1 << 18), bk, bv,
                                                 SCALE * 1.4426950408889634f, kp, vp);
  attn_stats<<<2048, 256, 0, stream>>>(qp, kp, vp, Vt);
  attn_out<<<2048, 256, 0, stream>>>(qp, kp, Vt, ohb);
  ln_k<1, 0><<<8192, 256, 0, stream>>>(ohb, qp, g0, be0, x0b, nullptr);
  gemm_bf16a<<<dim3(256, 4), 256, 0, stream>>>(x0b, Wt + 3 * (1 << 18), bo, oh2);
  ln_k<0, 1><<<8192, 256, 0, stream>>>(oh2, nullptr, g1, be1, nullptr, outp);
}

// Round 3
// 493.697 us; speedup vs baseline: 1.1751x; 1.1751x over previous
//
#include <hip/hip_runtime.h>

#define Bz  32
#define NQz 1024
#define NKz 1024
#define SCALE 0.04419417382415922f  // 1/sqrt(512)

typedef __bf16 bf16_t;
typedef bf16_t bf16x8 __attribute__((ext_vector_type(8)));
typedef bf16_t bf16x4 __attribute__((ext_vector_type(4)));
typedef float  f32x4  __attribute__((ext_vector_type(4)));

#define MFMA16(a, b, c) __builtin_amdgcn_mfma_f32_16x16x32_bf16(a, b, c, 0, 0, 0)

// raw barrier + counted waitcnt: loads stay in flight across barriers
#define SBAR() asm volatile("s_barrier" ::: "memory")
#define WAITVM(n) asm volatile("s_waitcnt vmcnt(" #n ")" ::: "memory")
#define WAITVL(n) asm volatile("s_waitcnt vmcnt(" #n ") lgkmcnt(0)" ::: "memory")

// async global->LDS DMA, 16B per lane; LDS dest = lptr + lane*16 (wave-uniform base)
__device__ __forceinline__ void gll16(const void* g, void* l) {
  __builtin_amdgcn_global_load_lds(
      (const __attribute__((address_space(1))) void*)g,
      (__attribute__((address_space(3))) void*)l, 16, 0, 0);
}

// native exp2 (K pre-scaled by log2e, so exp(s) == exp2(s'))
__device__ __forceinline__ float fexp2(float x) {
#if __has_builtin(__builtin_amdgcn_exp2f)
  return __builtin_amdgcn_exp2f(x);
#else
  float r;
  asm("v_exp_f32 %0, %1" : "=v"(r) : "v"(x));
  return r;
#endif
}

__device__ __forceinline__ bf16x8 cvt8(float4 a, float4 b) {
  bf16x8 r;
  r[0] = (bf16_t)a.x; r[1] = (bf16_t)a.y; r[2] = (bf16_t)a.z; r[3] = (bf16_t)a.w;
  r[4] = (bf16_t)b.x; r[5] = (bf16_t)b.y; r[6] = (bf16_t)b.z; r[7] = (bf16_t)b.w;
  return r;
}

// ---- transpose + bf16-convert the four 512x512 weight matrices: Wt[n][k] = W[k][n]
__global__ void transpose_w(const float* __restrict__ W0, const float* __restrict__ W1,
                            const float* __restrict__ W2, const float* __restrict__ W3,
                            bf16_t* __restrict__ out) {
  __shared__ float tile[32][33];
  const float* W = blockIdx.z == 0 ? W0 : blockIdx.z == 1 ? W1 : blockIdx.z == 2 ? W2 : W3;
  bf16_t* o = out + (size_t)blockIdx.z * 512 * 512;
  const int n0 = blockIdx.x * 32, k0 = blockIdx.y * 32;
  const int tx = threadIdx.x, ty = threadIdx.y;  // (32,8)
  for (int i = 0; i < 4; i++)
    tile[ty + i * 8][tx] = W[(size_t)(k0 + ty + i * 8) * 512 + n0 + tx];
  __syncthreads();
  for (int i = 0; i < 4; i++)
    o[(size_t)(n0 + ty + i * 8) * 512 + k0 + tx] = (bf16_t)tile[tx][ty + i * 8];
}

// ===================== projection GEMMs (A = fp32 input) =====================
// 128x128 tile, double-buffered W staging (DMA, counted vmcnt) + A-register
// prefetch; 2 barriers/iter (single-buffered As needs the end barrier).
// DUAL=0: C0 = bf16((A@W + b0) * mult0), grid.y=4.
// DUAL=1: W spans [1024][512] (Wk||Wv); n0<512 -> C0 (bias b0, mult0),
//         else C1 (bias b1, mult 1). grid.y=8.
template <int DUAL>
__global__ __launch_bounds__(256) void gemm_f32a(const float* __restrict__ A,
                                                 const bf16_t* __restrict__ Wt,
                                                 const float* __restrict__ b0v,
                                                 const float* __restrict__ b1v,
                                                 float mult0,
                                                 bf16_t* __restrict__ C0,
                                                 bf16_t* __restrict__ C1) {
  __shared__ __align__(16) bf16_t As[128][40];
  __shared__ __align__(16) bf16_t Bs[2][128 * 32];
  const int t = threadIdx.x;
  const int wave = t >> 6, lane = t & 63;
  const int quad = lane >> 4, l16 = lane & 15;
  const int wm = wave & 1, wn = wave >> 1;
  const int m0 = blockIdx.x * 128, n0 = blockIdx.y * 128;
  const int r = t >> 1, half = t & 1;
  // DMA mapping: pass p -> row p*64 + wave*16 + (lane>>2), src granule (lane&3)^((lane>>3)&3)
  const int drow = lane >> 2;
  const int dg = (lane & 3) ^ ((lane >> 3) & 3);

  f32x4 acc[4][4] = {};

  const float* arow = A + (size_t)(m0 + r) * 512 + half * 16;
  const bf16_t* wrow = Wt + (size_t)(n0 + wave * 16 + drow) * 512 + dg * 8;

  // prologue: tile 0 in flight + A(0) regs
  for (int p = 0; p < 2; p++)
    gll16(wrow + (size_t)(p * 64) * 512, &Bs[0][(p * 256 + wave * 64) * 8]);
  float4 a0 = *(const float4*)(arow + 0);
  float4 a1 = *(const float4*)(arow + 4);
  float4 a2 = *(const float4*)(arow + 8);
  float4 a3 = *(const float4*)(arow + 12);

  for (int it = 0; it < 16; it++) {
    const int cur = it & 1;
    if (it < 15)
      for (int p = 0; p < 2; p++)
        gll16(wrow + (it + 1) * 32 + (size_t)(p * 64) * 512,
              &Bs[cur ^ 1][(p * 256 + wave * 64) * 8]);
    *(bf16x8*)&As[r][half * 16 + 0] = cvt8(a0, a1);
    *(bf16x8*)&As[r][half * 16 + 8] = cvt8(a2, a3);
    if (it < 15) {
      const float* ap = arow + (it + 1) * 32;
      a0 = *(const float4*)(ap + 0);
      a1 = *(const float4*)(ap + 4);
      a2 = *(const float4*)(ap + 8);
      a3 = *(const float4*)(ap + 12);
      WAITVL(6);  // 2 gll16(it+1) + 4 A loads newer; tile it done, As drained
    } else {
      WAITVL(0);
    }
    SBAR();
    bf16x8 af[4], bfv[4];
    for (int mt = 0; mt < 4; mt++)
      af[mt] = *(const bf16x8*)&As[wm * 64 + mt * 16 + l16][quad * 8];
    for (int nt = 0; nt < 4; nt++) {
      const int rB = wn * 64 + nt * 16 + l16;
      bfv[nt] = *(const bf16x8*)&Bs[cur][rB * 32 + ((quad ^ ((rB >> 1) & 3)) * 8)];
    }
    for (int mt = 0; mt < 4; mt++)
      for (int nt = 0; nt < 4; nt++)
        acc[mt][nt] = MFMA16(af[mt], bfv[nt], acc[mt][nt]);
    SBAR();  // all waves done reading As/Bs[cur] before next-iter restage
  }

  const float* bias = (!DUAL || n0 < 512) ? b0v : b1v;
  bf16_t* C = (!DUAL || n0 < 512) ? C0 : C1;
  const float mult = (!DUAL || n0 < 512) ? mult0 : 1.0f;
  const int nb = (!DUAL || n0 < 512) ? n0 : n0 - 512;
  for (int mt = 0; mt < 4; mt++) {
    for (int nt = 0; nt < 4; nt++) {
      const int row = m0 + wm * 64 + mt * 16 + quad * 4;
      const int col = nb + wn * 64 + nt * 16 + l16;
      const float bv = bias[col];
      for (int rg = 0; rg < 4; rg++)
        C[(size_t)(row + rg) * 512 + col] = (bf16_t)((acc[mt][nt][rg] + bv) * mult);
    }
  }
}

// ===================== output GEMM (A = bf16, resid+relu epilogue) ===========
__global__ __launch_bounds__(256) void gemm_bf16a(const bf16_t* __restrict__ A,
                                                  const bf16_t* __restrict__ Wt,
                                                  const float* __restrict__ bias,
                                                  bf16_t* __restrict__ C) {
  __shared__ __align__(16) bf16_t As[128][40];
  __shared__ __align__(16) bf16_t Bs[2][128 * 32];
  const int t = threadIdx.x;
  const int wave = t >> 6, lane = t & 63;
  const int quad = lane >> 4, l16 = lane & 15;
  const int wm = wave & 1, wn = wave >> 1;
  const int m0 = blockIdx.x * 128, n0 = blockIdx.y * 128;
  const int r = t >> 1, half = t & 1;
  const int drow = lane >> 2;
  const int dg = (lane & 3) ^ ((lane >> 3) & 3);

  f32x4 acc[4][4] = {};

  const bf16_t* arow = A + (size_t)(m0 + r) * 512 + half * 16;
  const bf16_t* wrow = Wt + (size_t)(n0 + wave * 16 + drow) * 512 + dg * 8;

  for (int p = 0; p < 2; p++)
    gll16(wrow + (size_t)(p * 64) * 512, &Bs[0][(p * 256 + wave * 64) * 8]);
  bf16x8 v0 = *(const bf16x8*)(arow + 0);
  bf16x8 v1 = *(const bf16x8*)(arow + 8);

  for (int it = 0; it < 16; it++) {
    const int cur = it & 1;
    if (it < 15)
      for (int p = 0; p < 2; p++)
        gll16(wrow + (it + 1) * 32 + (size_t)(p * 64) * 512,
              &Bs[cur ^ 1][(p * 256 + wave * 64) * 8]);
    *(bf16x8*)&As[r][half * 16 + 0] = v0;
    *(bf16x8*)&As[r][half * 16 + 8] = v1;
    if (it < 15) {
      const bf16_t* ap = arow + (it + 1) * 32;
      v0 = *(const bf16x8*)(ap + 0);
      v1 = *(const bf16x8*)(ap + 8);
      WAITVL(4);  // 2 gll16(it+1) + 2 A loads newer; tile it done
    } else {
      WAITVL(0);
    }
    SBAR();
    bf16x8 af[4], bfv[4];
    for (int mt = 0; mt < 4; mt++)
      af[mt] = *(const bf16x8*)&As[wm * 64 + mt * 16 + l16][quad * 8];
    for (int nt = 0; nt < 4; nt++) {
      const int rB = wn * 64 + nt * 16 + l16;
      bfv[nt] = *(const bf16x8*)&Bs[cur][rB * 32 + ((quad ^ ((rB >> 1) & 3)) * 8)];
    }
    for (int mt = 0; mt < 4; mt++)
      for (int nt = 0; nt < 4; nt++)
        acc[mt][nt] = MFMA16(af[mt], bfv[nt], acc[mt][nt]);
    SBAR();
  }

  for (int mt = 0; mt < 4; mt++) {
    for (int nt = 0; nt < 4; nt++) {
      const int row = m0 + wm * 64 + mt * 16 + quad * 4;
      const int col = n0 + wn * 64 + nt * 16 + l16;
      const float bv = bias[col];
      for (int rg = 0; rg < 4; rg++) {
        float v = acc[mt][nt][rg] + bv;
        float x = (float)A[(size_t)(row + rg) * 512 + col];
        C[(size_t)(row + rg) * 512 + col] = (bf16_t)(x + fmaxf(v, 0.f));
      }
    }
  }
}

// ---- stats: l_k = sum_q exp(s[q,k]) (kp pre-scaled by SCALE*log2e -> exp2).
// Writes Vt[hb][d][k] = V[k][d]/l_k. Grid 2048 (XCD-swizzled). K A-frags in
// regs; Q tiles double-buffered DMA (XOR swizzle g^(row&7)).
// ONE barrier per iter: WAITVM(0)+SBAR at top, DMA issue AFTER the barrier
// (prefetch targets buf^1, whose last readers finished before SBAR).
__global__ __launch_bounds__(256) void attn_stats(const bf16_t* __restrict__ qp,
                                                  const bf16_t* __restrict__ kp,
                                                  const bf16_t* __restrict__ vp,
                                                  bf16_t* __restrict__ Vt) {
  __shared__ __align__(16) bf16_t Vs[128][72];
  __shared__ __align__(16) bf16_t Qs[2][64 * 64];
  __shared__ float ls[128];
  const int t = threadIdx.x;
  const int wave = t >> 6, lane = t & 63;
  const int quad = lane >> 4, l16 = lane & 15;
  const int id = blockIdx.x;
  const int kb = ((id >> 3) & 7) * 128;
  const int hb = (id & 7) * 32 + (id >> 6);
  const int h = hb >> 5, b = hb & 31;
  const bf16_t* qbase = qp + (size_t)b * NQz * 512 + h * 64;
  const bf16_t* kbase = kp + (size_t)b * NKz * 512 + h * 64;
  // DMA mapping (8 granules/row): row p*32+wave*8+(lane>>3), src granule (lane&7)^(lane>>3)
  const int drow = lane >> 3;
  const int dg = (lane & 7) ^ drow;

  {  // stage V block for the epilogue transpose
    const int r = t >> 1, half = t & 1;
    const bf16_t* vr = vp + (size_t)b * NKz * 512 + (size_t)(kb + r) * 512 + h * 64 + half * 32;
    *(bf16x8*)&Vs[r][half * 32 + 0]  = *(const bf16x8*)(vr + 0);
    *(bf16x8*)&Vs[r][half * 32 + 8]  = *(const bf16x8*)(vr + 8);
    *(bf16x8*)&Vs[r][half * 32 + 16] = *(const bf16x8*)(vr + 16);
    *(bf16x8*)&Vs[r][half * 32 + 24] = *(const bf16x8*)(vr + 24);
  }

  bf16x8 aK[2][2];
  for (int mt = 0; mt < 2; mt++) {
    const bf16_t* kr = kbase + (size_t)(kb + wave * 32 + mt * 16 + l16) * 512 + quad * 8;
    aK[mt][0] = *(const bf16x8*)kr;
    aK[mt][1] = *(const bf16x8*)(kr + 32);
  }

  // prologue: q-tile 0 in flight
  for (int p = 0; p < 2; p++) {
    const bf16_t* src = qbase + (size_t)(p * 32 + wave * 8 + drow) * 512 + dg * 8;
    gll16(src, &Qs[0][(p * 256 + wave * 64) * 8]);
  }

  const f32x4 fz = {0.f, 0.f, 0.f, 0.f};
  f32x4 lacc[2] = {};
  for (int it = 0; it < 16; it++) {
    const int cur = it & 1;
    WAITVM(0);  // own DMAs for tile it complete (nothing newer in flight)
    SBAR();     // all waves' DMAs done; all waves done reading buf^1 (iter it-1)
    if (it < 15) {
      const int qn = (it + 1) * 64;
      for (int p = 0; p < 2; p++) {
        const bf16_t* src = qbase + (size_t)(qn + p * 32 + wave * 8 + drow) * 512 + dg * 8;
        gll16(src, &Qs[cur ^ 1][(p * 256 + wave * 64) * 8]);
      }
    }
    for (int nt = 0; nt < 4; nt++) {
      const int rQ = nt * 16 + l16;
      bf16x8 b0 = *(const bf16x8*)&Qs[cur][rQ * 64 + ((quad ^ (rQ & 7)) * 8)];
      bf16x8 b1 = *(const bf16x8*)&Qs[cur][rQ * 64 + (((quad + 4) ^ (rQ & 7)) * 8)];
      for (int mt = 0; mt < 2; mt++) {
        f32x4 s = MFMA16(aK[mt][0], b0, fz);
        s = MFMA16(aK[mt][1], b1, s);
        lacc[mt][0] += fexp2(s[0]);
        lacc[mt][1] += fexp2(s[1]);
        lacc[mt][2] += fexp2(s[2]);
        lacc[mt][3] += fexp2(s[3]);
      }
    }
  }
  for (int mt = 0; mt < 2; mt++) {
    for (int rg = 0; rg < 4; rg++) {
      float v = lacc[mt][rg];
      v += __shfl_xor(v, 1);
      v += __shfl_xor(v, 2);
      v += __shfl_xor(v, 4);
      v += __shfl_xor(v, 8);
      if (l16 == 0) ls[wave * 32 + mt * 16 + quad * 4 + rg] = 1.0f / v;
    }
  }
  __syncthreads();
  const int d = t >> 2, kc = (t & 3) * 32;
  bf16_t* vtr = Vt + (size_t)hb * 64 * 1024 + (size_t)d * 1024 + kb + kc;
  for (int c = 0; c < 4; c++) {
    bf16x8 o;
    for (int j = 0; j < 8; j++)
      o[j] = (bf16_t)((float)Vs[kc + c * 8 + j][d] * ls[kc + c * 8 + j]);
    *(bf16x8*)(vtr + c * 8) = o;
  }
}

// ---- attn_out: O[q,d] = sum_k exp(s[q,k]) * Vt[d,k].  Grid 2048 (XCD-swizzled).
// K-tile + Vt-tile double-buffered DMA (XOR swizzle); Q B-frags in regs; P via
// wave-private Ps rows (b64 writes).
// ONE barrier per iter: WAITVM(0)+SBAR at top, DMA issue AFTER the barrier.
__global__ __launch_bounds__(256) void attn_out(const bf16_t* __restrict__ qp,
                                                const bf16_t* __restrict__ kp,
                                                const bf16_t* __restrict__ Vt,
                                                bf16_t* __restrict__ oh) {
  __shared__ __align__(16) bf16_t Ks[2][64 * 64];
  __shared__ __align__(16) bf16_t Vts[2][64 * 64];
  __shared__ __align__(16) bf16_t Ps[128][72];
  const int t = threadIdx.x;
  const int wave = t >> 6, lane = t & 63;
  const int quad = lane >> 4, l16 = lane & 15;
  const int id = blockIdx.x;
  const int qt = (id >> 3) & 7;
  const int hb = (id & 7) * 32 + (id >> 6);
  const int h = hb >> 5, b = hb & 31;
  const int q0 = qt * 128;
  const bf16_t* qbase = qp + (size_t)b * NQz * 512 + h * 64;
  const bf16_t* kbase = kp + (size_t)b * NKz * 512 + h * 64;
  const bf16_t* vtbase = Vt + (size_t)hb * 64 * 1024;
  const int drow = lane >> 3;
  const int dg = (lane & 7) ^ drow;

  bf16x8 bQ[2][2];
  for (int nt = 0; nt < 2; nt++) {
    const bf16_t* qr = qbase + (size_t)(q0 + wave * 32 + nt * 16 + l16) * 512 + quad * 8;
    bQ[nt][0] = *(const bf16x8*)qr;
    bQ[nt][1] = *(const bf16x8*)(qr + 32);
  }

  // prologue: tile 0 (K + Vt) in flight
  for (int p = 0; p < 2; p++) {
    const bf16_t* ksrc = kbase + (size_t)(p * 32 + wave * 8 + drow) * 512 + dg * 8;
    gll16(ksrc, &Ks[0][(p * 256 + wave * 64) * 8]);
    const bf16_t* vsrc = vtbase + (size_t)(p * 32 + wave * 8 + drow) * 1024 + dg * 8;
    gll16(vsrc, &Vts[0][(p * 256 + wave * 64) * 8]);
  }

  const f32x4 fz = {0.f, 0.f, 0.f, 0.f};
  f32x4 acc[2][4] = {};
  for (int it = 0; it < 16; it++) {
    const int kk = it * 64;
    const int cur = it & 1;
    WAITVM(0);  // own DMAs for tile it complete (nothing newer in flight)
    SBAR();     // all waves' DMAs done; all waves done reading buf^1 (iter it-1)
    if (it < 15) {
      const int kn = kk + 64;
      for (int p = 0; p < 2; p++) {
        const bf16_t* ksrc = kbase + (size_t)(kn + p * 32 + wave * 8 + drow) * 512 + dg * 8;
        gll16(ksrc, &Ks[cur ^ 1][(p * 256 + wave * 64) * 8]);
        const bf16_t* vsrc = vtbase + (size_t)(p * 32 + wave * 8 + drow) * 1024 + kn + dg * 8;
        gll16(vsrc, &Vts[cur ^ 1][(p * 256 + wave * 64) * 8]);
      }
    }
    // S^T: m = k (A-frag from Ks), n = q (regs). C rows = 4 consecutive k -> b64 pack.
    for (int mt = 0; mt < 4; mt++) {
      const int rK = mt * 16 + l16;
      bf16x8 a0 = *(const bf16x8*)&Ks[cur][rK * 64 + ((quad ^ (rK & 7)) * 8)];
      bf16x8 a1 = *(const bf16x8*)&Ks[cur][rK * 64 + (((quad + 4) ^ (rK & 7)) * 8)];
      for (int nt = 0; nt < 2; nt++) {
        f32x4 s = MFMA16(a0, bQ[nt][0], fz);
        s = MFMA16(a1, bQ[nt][1], s);
        bf16x4 pk;
        pk[0] = (bf16_t)fexp2(s[0]);
        pk[1] = (bf16_t)fexp2(s[1]);
        pk[2] = (bf16_t)fexp2(s[2]);
        pk[3] = (bf16_t)fexp2(s[3]);
        *(bf16x4*)&Ps[wave * 32 + nt * 16 + l16][mt * 16 + quad * 4] = pk;
      }
    }
    // PV: A-frag = Ps rows (wave-private, b128), B-frag = Vts rows (swizzled b128).
    bf16x8 aP[2][2];
    for (int mt = 0; mt < 2; mt++) {
      aP[mt][0] = *(const bf16x8*)&Ps[wave * 32 + mt * 16 + l16][quad * 8];
      aP[mt][1] = *(const bf16x8*)&Ps[wave * 32 + mt * 16 + l16][quad * 8 + 32];
    }
    for (int nd = 0; nd < 4; nd++) {
      const int rV = nd * 16 + l16;
      bf16x8 b0 = *(const bf16x8*)&Vts[cur][rV * 64 + ((quad ^ (rV & 7)) * 8)];
      bf16x8 b1 = *(const bf16x8*)&Vts[cur][rV * 64 + (((quad + 4) ^ (rV & 7)) * 8)];
      for (int mt = 0; mt < 2; mt++) {
        acc[mt][nd] = MFMA16(aP[mt][0], b0, acc[mt][nd]);
        acc[mt][nd] = MFMA16(aP[mt][1], b1, acc[mt][nd]);
      }
    }
  }
  for (int mt = 0; mt < 2; mt++)
    for (int nd = 0; nd < 4; nd++)
      for (int rg = 0; rg < 4; rg++)
        Ps[wave * 32 + mt * 16 + quad * 4 + rg][nd * 16 + l16] = (bf16_t)acc[mt][nd][rg];
  const int row = wave * 32 + (lane >> 1), cc = (lane & 1) * 32;
  bf16_t* orow = oh + ((size_t)b * NQz + q0 + row) * 512 + h * 64 + cc;
  for (int c = 0; c < 4; c++)
    *(bf16x8*)(orow + c * 8) = *(const bf16x8*)&Ps[row][cc + c * 8];
}

// ---- LayerNorm over 512 cols, one wave per row, bf16 in.
template <int RES, int F32OUT>
__global__ __launch_bounds__(256) void ln_k(const bf16_t* __restrict__ x,
                                            const bf16_t* __restrict__ res,
                                            const float* __restrict__ g,
                                            const float* __restrict__ be,
                                            bf16_t* __restrict__ yb,
                                            float* __restrict__ yf) {
  const int wave = threadIdx.x >> 6, lane = threadIdx.x & 63;
  const size_t row = (size_t)blockIdx.x * 4 + wave;
  bf16x8 xv = *(const bf16x8*)(x + row * 512 + lane * 8);
  float xf[8];
  for (int i = 0; i < 8; i++) xf[i] = (float)xv[i];
  if (RES) {
    bf16x8 rv = *(const bf16x8*)(res + row * 512 + lane * 8);
    for (int i = 0; i < 8; i++) xf[i] += (float)rv[i];
  }
  float s = 0.f, sq = 0.f;
  for (int i = 0; i < 8; i++) { s += xf[i]; sq += xf[i] * xf[i]; }
  for (int off = 1; off < 64; off <<= 1) {
    s += __shfl_xor(s, off);
    sq += __shfl_xor(sq, off);
  }
  const float mu = s * (1.0f / 512.0f);
  const float var = sq * (1.0f / 512.0f) - mu * mu;
  const float rstd = rsqrtf(var + 1e-5f);
  float4 gv0 = *(const float4*)(g + lane * 8);
  float4 gv1 = *(const float4*)(g + lane * 8 + 4);
  float4 bv0 = *(const float4*)(be + lane * 8);
  float4 bv1 = *(const float4*)(be + lane * 8 + 4);
  float gg[8] = {gv0.x, gv0.y, gv0.z, gv0.w, gv1.x, gv1.y, gv1.z, gv1.w};
  float bb[8] = {bv0.x, bv0.y, bv0.z, bv0.w, bv1.x, bv1.y, bv1.z, bv1.w};
  float o[8];
  for (int i = 0; i < 8; i++) o[i] = (xf[i] - mu) * rstd * gg[i] + bb[i];
  if (F32OUT) {
    float4 o0 = {o[0], o[1], o[2], o[3]}, o1 = {o[4], o[5], o[6], o[7]};
    *(float4*)(yf + row * 512 + lane * 8) = o0;
    *(float4*)(yf + row * 512 + lane * 8 + 4) = o1;
  } else {
    bf16x8 ov;
    for (int i = 0; i < 8; i++) ov[i] = (bf16_t)o[i];
    *(bf16x8*)(yb + row * 512 + lane * 8) = ov;
  }
}

extern "C" void kernel_launch(void* const* d_in, const int* in_sizes, int n_in,
                              void* d_out, int out_size, void* d_ws, size_t ws_size,
                              hipStream_t stream) {
  (void)in_sizes; (void)n_in; (void)out_size; (void)ws_size;
  const float* Q   = (const float*)d_in[0];
  const float* K   = (const float*)d_in[1];
  const float* Wq  = (const float*)d_in[2];
  const float* bq  = (const float*)d_in[3];
  const float* Wk  = (const float*)d_in[4];
  const float* bk  = (const float*)d_in[5];
  const float* Wv  = (const float*)d_in[6];
  const float* bv  = (const float*)d_in[7];
  const float* Wo  = (const float*)d_in[8];
  const float* bo  = (const float*)d_in[9];
  const float* g0  = (const float*)d_in[10];
  const float* be0 = (const float*)d_in[11];
  const float* g1  = (const float*)d_in[12];
  const float* be1 = (const float*)d_in[13];
  float* outp = (float*)d_out;

  char* w = (char*)d_ws;
  bf16_t* Wt  = (bf16_t*)w;                     // 2 MB (4 x 512x512 bf16)
  bf16_t* qp  = (bf16_t*)(w + (2ull << 20));    // 32 MB (Q proj; residual source)
  bf16_t* kp  = (bf16_t*)(w + (34ull << 20));   // 32 MB (K proj, pre-scaled by SCALE*log2e)
  bf16_t* vp  = (bf16_t*)(w + (66ull << 20));   // 32 MB (V proj, dead after stats)
  bf16_t* Vt  = (bf16_t*)(w + (98ull << 20));   // 32 MB (V'/l transposed [hb][64][1024])
  bf16_t* ohb = (bf16_t*)(w + (130ull << 20));  // 32 MB (attn out, no resid)
  bf16_t* x0b = vp;                             // reuse: LN0 out
  bf16_t* oh2 = kp;                             // reuse: out-proj+relu+resid

  transpose_w<<<dim3(16, 16, 4), dim3(32, 8), 0, stream>>>(Wq, Wk, Wv, Wo, Wt);
  gemm_f32a<0><<<dim3(256, 4), 256, 0, stream>>>(Q, Wt, bq, nullptr, 1.0f, qp, nullptr);
  // fold log2(e) into K so attn kernels use native v_exp_f32 (exp2)
  gemm_f32a<1><<<dim3(256, 8), 256, 0, stream>>>(K, Wt + (1 << 18), bk, bv,
                                                 SCALE * 1.4426950408889634f, kp, vp);
  attn_stats<<<2048, 256, 0, stream>>>(qp, kp, vp, Vt);
  attn_out<<<2048, 256, 0, stream>>>(qp, kp, Vt, ohb);
  ln_k<1, 0><<<8192, 256, 0, stream>>>(ohb, qp, g0, be0, x0b, nullptr);
  gemm_bf16a<<<dim3(256, 4), 256, 0, stream>>>(x0b, Wt + 3 * (1 << 18), bo, oh2);
  ln_k<0, 1><<<8192, 256, 0, stream>>>(oh2, nullptr, g1, be1, nullptr, outp);
}

// Round 5
// 478.580 us; speedup vs baseline: 1.2122x; 1.0316x over previous
//
#include <hip/hip_runtime.h>

#define Bz  32
#define NQz 1024
#define NKz 1024
#define SCALE 0.04419417382415922f  // 1/sqrt(512)

typedef __bf16 bf16_t;
typedef bf16_t bf16x8 __attribute__((ext_vector_type(8)));
typedef bf16_t bf16x4 __attribute__((ext_vector_type(4)));
typedef float  f32x4  __attribute__((ext_vector_type(4)));

#define MFMA16(a, b, c) __builtin_amdgcn_mfma_f32_16x16x32_bf16(a, b, c, 0, 0, 0)

// raw barrier + counted waitcnt: loads stay in flight across barriers
#define SBAR() asm volatile("s_barrier" ::: "memory")
#define WAITVM(n) asm volatile("s_waitcnt vmcnt(" #n ")" ::: "memory")
#define WAITVL(n) asm volatile("s_waitcnt vmcnt(" #n ") lgkmcnt(0)" ::: "memory")

// async global->LDS DMA, 16B per lane; LDS dest = lptr + lane*16 (wave-uniform base)
__device__ __forceinline__ void gll16(const void* g, void* l) {
  __builtin_amdgcn_global_load_lds(
      (const __attribute__((address_space(1))) void*)g,
      (__attribute__((address_space(3))) void*)l, 16, 0, 0);
}

// native exp2 (K pre-scaled by log2e, so exp(s) == exp2(s'))
__device__ __forceinline__ float fexp2(float x) {
#if __has_builtin(__builtin_amdgcn_exp2f)
  return __builtin_amdgcn_exp2f(x);
#else
  float r;
  asm("v_exp_f32 %0, %1" : "=v"(r) : "v"(x));
  return r;
#endif
}

__device__ __forceinline__ bf16x8 cvt8(float4 a, float4 b) {
  bf16x8 r;
  r[0] = (bf16_t)a.x; r[1] = (bf16_t)a.y; r[2] = (bf16_t)a.z; r[3] = (bf16_t)a.w;
  r[4] = (bf16_t)b.x; r[5] = (bf16_t)b.y; r[6] = (bf16_t)b.z; r[7] = (bf16_t)b.w;
  return r;
}

// ---- transpose + bf16-convert the four 512x512 weight matrices: Wt[n][k] = W[k][n]
__global__ void transpose_w(const float* __restrict__ W0, const float* __restrict__ W1,
                            const float* __restrict__ W2, const float* __restrict__ W3,
                            bf16_t* __restrict__ out) {
  __shared__ float tile[32][33];
  const float* W = blockIdx.z == 0 ? W0 : blockIdx.z == 1 ? W1 : blockIdx.z == 2 ? W2 : W3;
  bf16_t* o = out + (size_t)blockIdx.z * 512 * 512;
  const int n0 = blockIdx.x * 32, k0 = blockIdx.y * 32;
  const int tx = threadIdx.x, ty = threadIdx.y;  // (32,8)
  for (int i = 0; i < 4; i++)
    tile[ty + i * 8][tx] = W[(size_t)(k0 + ty + i * 8) * 512 + n0 + tx];
  __syncthreads();
  for (int i = 0; i < 4; i++)
    o[(size_t)(n0 + ty + i * 8) * 512 + k0 + tx] = (bf16_t)tile[tx][ty + i * 8];
}

// ===================== projection GEMMs (A = fp32 input) =====================
// 128x128 tile, double-buffered W staging (DMA, counted vmcnt) + A-register
// prefetch; 2 barriers/iter (single-buffered As needs the end barrier).
// DUAL=0: C0 = bf16((A@W + b0) * mult0), grid.y=4.
// DUAL=1: W spans [1024][512] (Wk||Wv); n0<512 -> C0 (bias b0, mult0),
//         else C1 (bias b1, mult 1). grid.y=8.
template <int DUAL>
__global__ __launch_bounds__(256) void gemm_f32a(const float* __restrict__ A,
                                                 const bf16_t* __restrict__ Wt,
                                                 const float* __restrict__ b0v,
                                                 const float* __restrict__ b1v,
                                                 float mult0,
                                                 bf16_t* __restrict__ C0,
                                                 bf16_t* __restrict__ C1) {
  __shared__ __align__(16) bf16_t As[128][40];
  __shared__ __align__(16) bf16_t Bs[2][128 * 32];
  const int t = threadIdx.x;
  const int wave = t >> 6, lane = t & 63;
  const int quad = lane >> 4, l16 = lane & 15;
  const int wm = wave & 1, wn = wave >> 1;
  const int m0 = blockIdx.x * 128, n0 = blockIdx.y * 128;
  const int r = t >> 1, half = t & 1;
  // DMA mapping: pass p -> row p*64 + wave*16 + (lane>>2), src granule (lane&3)^((lane>>3)&3)
  const int drow = lane >> 2;
  const int dg = (lane & 3) ^ ((lane >> 3) & 3);

  f32x4 acc[4][4] = {};

  const float* arow = A + (size_t)(m0 + r) * 512 + half * 16;
  const bf16_t* wrow = Wt + (size_t)(n0 + wave * 16 + drow) * 512 + dg * 8;

  // prologue: tile 0 in flight + A(0) regs
  for (int p = 0; p < 2; p++)
    gll16(wrow + (size_t)(p * 64) * 512, &Bs[0][(p * 256 + wave * 64) * 8]);
  float4 a0 = *(const float4*)(arow + 0);
  float4 a1 = *(const float4*)(arow + 4);
  float4 a2 = *(const float4*)(arow + 8);
  float4 a3 = *(const float4*)(arow + 12);

  for (int it = 0; it < 16; it++) {
    const int cur = it & 1;
    if (it < 15)
      for (int p = 0; p < 2; p++)
        gll16(wrow + (it + 1) * 32 + (size_t)(p * 64) * 512,
              &Bs[cur ^ 1][(p * 256 + wave * 64) * 8]);
    *(bf16x8*)&As[r][half * 16 + 0] = cvt8(a0, a1);
    *(bf16x8*)&As[r][half * 16 + 8] = cvt8(a2, a3);
    if (it < 15) {
      const float* ap = arow + (it + 1) * 32;
      a0 = *(const float4*)(ap + 0);
      a1 = *(const float4*)(ap + 4);
      a2 = *(const float4*)(ap + 8);
      a3 = *(const float4*)(ap + 12);
      WAITVL(6);  // 2 gll16(it+1) + 4 A loads newer; tile it done, As drained
    } else {
      WAITVL(0);
    }
    SBAR();
    bf16x8 af[4], bfv[4];
    for (int mt = 0; mt < 4; mt++)
      af[mt] = *(const bf16x8*)&As[wm * 64 + mt * 16 + l16][quad * 8];
    for (int nt = 0; nt < 4; nt++) {
      const int rB = wn * 64 + nt * 16 + l16;
      bfv[nt] = *(const bf16x8*)&Bs[cur][rB * 32 + ((quad ^ ((rB >> 1) & 3)) * 8)];
    }
    for (int mt = 0; mt < 4; mt++)
      for (int nt = 0; nt < 4; nt++)
        acc[mt][nt] = MFMA16(af[mt], bfv[nt], acc[mt][nt]);
    SBAR();  // all waves done reading As/Bs[cur] before next-iter restage
  }

  const float* bias = (!DUAL || n0 < 512) ? b0v : b1v;
  bf16_t* C = (!DUAL || n0 < 512) ? C0 : C1;
  const float mult = (!DUAL || n0 < 512) ? mult0 : 1.0f;
  const int nb = (!DUAL || n0 < 512) ? n0 : n0 - 512;
  for (int mt = 0; mt < 4; mt++) {
    for (int nt = 0; nt < 4; nt++) {
      const int row = m0 + wm * 64 + mt * 16 + quad * 4;
      const int col = nb + wn * 64 + nt * 16 + l16;
      const float bv = bias[col];
      for (int rg = 0; rg < 4; rg++)
        C[(size_t)(row + rg) * 512 + col] = (bf16_t)((acc[mt][nt][rg] + bv) * mult);
    }
  }
}

// ===================== output GEMM (A = bf16, resid+relu epilogue) ===========
__global__ __launch_bounds__(256) void gemm_bf16a(const bf16_t* __restrict__ A,
                                                  const bf16_t* __restrict__ Wt,
                                                  const float* __restrict__ bias,
                                                  bf16_t* __restrict__ C) {
  __shared__ __align__(16) bf16_t As[128][40];
  __shared__ __align__(16) bf16_t Bs[2][128 * 32];
  const int t = threadIdx.x;
  const int wave = t >> 6, lane = t & 63;
  const int quad = lane >> 4, l16 = lane & 15;
  const int wm = wave & 1, wn = wave >> 1;
  const int m0 = blockIdx.x * 128, n0 = blockIdx.y * 128;
  const int r = t >> 1, half = t & 1;
  const int drow = lane >> 2;
  const int dg = (lane & 3) ^ ((lane >> 3) & 3);

  f32x4 acc[4][4] = {};

  const bf16_t* arow = A + (size_t)(m0 + r) * 512 + half * 16;
  const bf16_t* wrow = Wt + (size_t)(n0 + wave * 16 + drow) * 512 + dg * 8;

  for (int p = 0; p < 2; p++)
    gll16(wrow + (size_t)(p * 64) * 512, &Bs[0][(p * 256 + wave * 64) * 8]);
  bf16x8 v0 = *(const bf16x8*)(arow + 0);
  bf16x8 v1 = *(const bf16x8*)(arow + 8);

  for (int it = 0; it < 16; it++) {
    const int cur = it & 1;
    if (it < 15)
      for (int p = 0; p < 2; p++)
        gll16(wrow + (it + 1) * 32 + (size_t)(p * 64) * 512,
              &Bs[cur ^ 1][(p * 256 + wave * 64) * 8]);
    *(bf16x8*)&As[r][half * 16 + 0] = v0;
    *(bf16x8*)&As[r][half * 16 + 8] = v1;
    if (it < 15) {
      const bf16_t* ap = arow + (it + 1) * 32;
      v0 = *(const bf16x8*)(ap + 0);
      v1 = *(const bf16x8*)(ap + 8);
      WAITVL(4);  // 2 gll16(it+1) + 2 A loads newer; tile it done
    } else {
      WAITVL(0);
    }
    SBAR();
    bf16x8 af[4], bfv[4];
    for (int mt = 0; mt < 4; mt++)
      af[mt] = *(const bf16x8*)&As[wm * 64 + mt * 16 + l16][quad * 8];
    for (int nt = 0; nt < 4; nt++) {
      const int rB = wn * 64 + nt * 16 + l16;
      bfv[nt] = *(const bf16x8*)&Bs[cur][rB * 32 + ((quad ^ ((rB >> 1) & 3)) * 8)];
    }
    for (int mt = 0; mt < 4; mt++)
      for (int nt = 0; nt < 4; nt++)
        acc[mt][nt] = MFMA16(af[mt], bfv[nt], acc[mt][nt]);
    SBAR();
  }

  for (int mt = 0; mt < 4; mt++) {
    for (int nt = 0; nt < 4; nt++) {
      const int row = m0 + wm * 64 + mt * 16 + quad * 4;
      const int col = n0 + wn * 64 + nt * 16 + l16;
      const float bv = bias[col];
      for (int rg = 0; rg < 4; rg++) {
        float v = acc[mt][nt][rg] + bv;
        float x = (float)A[(size_t)(row + rg) * 512 + col];
        C[(size_t)(row + rg) * 512 + col] = (bf16_t)(x + fmaxf(v, 0.f));
      }
    }
  }
}

// ---- stats: l_k = sum_q exp(s[q,k]) (kp pre-scaled by SCALE*log2e -> exp2).
// Writes Vt[hb][d][k] = V[k][d]/l_k. Grid 2048 (XCD-swizzled). K A-frags in
// regs; Q tiles double-buffered DMA (XOR swizzle g^(row&7)).
// ONE barrier per iter: WAITVM(0)+SBAR at top, DMA issue AFTER the barrier
// (prefetch targets buf^1, whose last readers finished before SBAR).
__global__ __launch_bounds__(256) void attn_stats(const bf16_t* __restrict__ qp,
                                                  const bf16_t* __restrict__ kp,
                                                  const bf16_t* __restrict__ vp,
                                                  bf16_t* __restrict__ Vt) {
  __shared__ __align__(16) bf16_t Vs[128][72];
  __shared__ __align__(16) bf16_t Qs[2][64 * 64];
  __shared__ float ls[128];
  const int t = threadIdx.x;
  const int wave = t >> 6, lane = t & 63;
  const int quad = lane >> 4, l16 = lane & 15;
  const int id = blockIdx.x;
  const int kb = ((id >> 3) & 7) * 128;
  const int hb = (id & 7) * 32 + (id >> 6);
  const int h = hb >> 5, b = hb & 31;
  const bf16_t* qbase = qp + (size_t)b * NQz * 512 + h * 64;
  const bf16_t* kbase = kp + (size_t)b * NKz * 512 + h * 64;
  // DMA mapping (8 granules/row): row p*32+wave*8+(lane>>3), src granule (lane&7)^(lane>>3)
  const int drow = lane >> 3;
  const int dg = (lane & 7) ^ drow;

  {  // stage V block for the epilogue transpose
    const int r = t >> 1, half = t & 1;
    const bf16_t* vr = vp + (size_t)b * NKz * 512 + (size_t)(kb + r) * 512 + h * 64 + half * 32;
    *(bf16x8*)&Vs[r][half * 32 + 0]  = *(const bf16x8*)(vr + 0);
    *(bf16x8*)&Vs[r][half * 32 + 8]  = *(const bf16x8*)(vr + 8);
    *(bf16x8*)&Vs[r][half * 32 + 16] = *(const bf16x8*)(vr + 16);
    *(bf16x8*)&Vs[r][half * 32 + 24] = *(const bf16x8*)(vr + 24);
  }

  bf16x8 aK[2][2];
  for (int mt = 0; mt < 2; mt++) {
    const bf16_t* kr = kbase + (size_t)(kb + wave * 32 + mt * 16 + l16) * 512 + quad * 8;
    aK[mt][0] = *(const bf16x8*)kr;
    aK[mt][1] = *(const bf16x8*)(kr + 32);
  }

  // prologue: q-tile 0 in flight
  for (int p = 0; p < 2; p++) {
    const bf16_t* src = qbase + (size_t)(p * 32 + wave * 8 + drow) * 512 + dg * 8;
    gll16(src, &Qs[0][(p * 256 + wave * 64) * 8]);
  }

  const f32x4 fz = {0.f, 0.f, 0.f, 0.f};
  f32x4 lacc[2] = {};
  for (int it = 0; it < 16; it++) {
    const int cur = it & 1;
    WAITVM(0);  // own DMAs for tile it complete (nothing newer in flight)
    SBAR();     // all waves' DMAs done; all waves done reading buf^1 (iter it-1)
    if (it < 15) {
      const int qn = (it + 1) * 64;
      for (int p = 0; p < 2; p++) {
        const bf16_t* src = qbase + (size_t)(qn + p * 32 + wave * 8 + drow) * 512 + dg * 8;
        gll16(src, &Qs[cur ^ 1][(p * 256 + wave * 64) * 8]);
      }
    }
    for (int nt = 0; nt < 4; nt++) {
      const int rQ = nt * 16 + l16;
      bf16x8 b0 = *(const bf16x8*)&Qs[cur][rQ * 64 + ((quad ^ (rQ & 7)) * 8)];
      bf16x8 b1 = *(const bf16x8*)&Qs[cur][rQ * 64 + (((quad + 4) ^ (rQ & 7)) * 8)];
      for (int mt = 0; mt < 2; mt++) {
        f32x4 s = MFMA16(aK[mt][0], b0, fz);
        s = MFMA16(aK[mt][1], b1, s);
        lacc[mt][0] += fexp2(s[0]);
        lacc[mt][1] += fexp2(s[1]);
        lacc[mt][2] += fexp2(s[2]);
        lacc[mt][3] += fexp2(s[3]);
      }
    }
  }
  for (int mt = 0; mt < 2; mt++) {
    for (int rg = 0; rg < 4; rg++) {
      float v = lacc[mt][rg];
      v += __shfl_xor(v, 1);
      v += __shfl_xor(v, 2);
      v += __shfl_xor(v, 4);
      v += __shfl_xor(v, 8);
      if (l16 == 0) ls[wave * 32 + mt * 16 + quad * 4 + rg] = 1.0f / v;
    }
  }
  __syncthreads();
  const int d = t >> 2, kc = (t & 3) * 32;
  bf16_t* vtr = Vt + (size_t)hb * 64 * 1024 + (size_t)d * 1024 + kb + kc;
  for (int c = 0; c < 4; c++) {
    bf16x8 o;
    for (int j = 0; j < 8; j++)
      o[j] = (bf16_t)((float)Vs[kc + c * 8 + j][d] * ls[kc + c * 8 + j]);
    *(bf16x8*)(vtr + c * 8) = o;
  }
}

// ---- attn_out: O[q,d] = sum_k exp(s[q,k]) * Vt[d,k].
// 8 waves / 512 threads, q-tile 256, k-tile 32, 32 iters. Grid 1024
// (XCD-swizzled). Waves 0-3 DMA-stage K (32 x 128B rows, 8-granule XOR
// swizzle row&7); waves 4-7 DMA-stage Vt (64 x 64B rows, 4-granule XOR
// swizzle row&3). 1 DMA/wave/iter, counted WAITVM(1). LDS pool 36.9KB:
// Ks dbuf + Vts dbuf + Ps[256][40]; O-epilogue aliases pool as [256][72].
__global__ __launch_bounds__(512, 6) void attn_out(const bf16_t* __restrict__ qp,
                                                   const bf16_t* __restrict__ kp,
                                                   const bf16_t* __restrict__ Vt,
                                                   bf16_t* __restrict__ oh) {
  __shared__ __align__(16) bf16_t pool[18432];  // 36864 B
  const int t = threadIdx.x;
  const int wave = t >> 6, lane = t & 63;
  const int quad = lane >> 4, l16 = lane & 15;
  const int id = blockIdx.x;
  const int qt = (id >> 3) & 3;
  const int hb = (id & 7) * 32 + (id >> 5);
  const int h = hb >> 5, b = hb & 31;
  const int q0 = qt * 256;
  const bf16_t* qbase = qp + (size_t)b * NQz * 512 + h * 64;
  const bf16_t* kbase = kp + (size_t)b * NKz * 512 + h * 64;
  const bf16_t* vtbase = Vt + (size_t)hb * 64 * 1024;

  // LDS layout (element offsets in pool):
  //   Ks(cur)  = pool + cur*2048           [32][64]
  //   Vts(cur) = pool + 4096 + cur*2048    [64][32]
  //   Ps       = pool + 8192               [256][40]
  bf16_t* const Ps = pool + 8192;

  // Q B-frags: wave's 32 q rows (2 x 16), full d=64
  bf16x8 bQ[2][2];
  for (int nt = 0; nt < 2; nt++) {
    const bf16_t* qr = qbase + (size_t)(q0 + wave * 32 + nt * 16 + l16) * 512 + quad * 8;
    bQ[nt][0] = *(const bf16x8*)qr;
    bQ[nt][1] = *(const bf16x8*)(qr + 32);
  }

  // staging geometry
  const bool stK = wave < 4;
  const int w4 = wave & 3;
  const int kdrow = w4 * 8 + (lane >> 3);          // k-row 0..31
  const int kdg = (lane & 7) ^ (lane >> 3);        // 8 granules/row, swz ^row&7
  const int vdrow = w4 * 16 + (lane >> 2);         // d-row 0..63
  const int vdg = (lane & 3) ^ ((lane >> 2) & 3);  // 4 granules/row, swz ^row&3

  // prologue: tile 0 in flight (1 DMA per wave)
  if (stK) gll16(kbase + (size_t)kdrow * 512 + kdg * 8, pool + w4 * 512);
  else     gll16(vtbase + (size_t)vdrow * 1024 + vdg * 8, pool + 4096 + w4 * 512);

  const f32x4 fz = {0.f, 0.f, 0.f, 0.f};
  f32x4 acc[2][4] = {};
  for (int it = 0; it < 32; it++) {
    const int cur = it & 1;
    const bf16_t* const Ksc  = pool + cur * 2048;
    const bf16_t* const Vtsc = pool + 4096 + cur * 2048;
    if (it < 31) {
      const int kn = (it + 1) * 32;
      bf16_t* const Ksn  = pool + (cur ^ 1) * 2048;
      bf16_t* const Vtsn = pool + 4096 + (cur ^ 1) * 2048;
      if (stK) gll16(kbase + (size_t)(kn + kdrow) * 512 + kdg * 8, Ksn + w4 * 512);
      else     gll16(vtbase + (size_t)vdrow * 1024 + kn + vdg * 8, Vtsn + w4 * 512);
      WAITVM(1);  // tile-it DMA done; tile-(it+1) stays in flight
    } else {
      WAITVM(0);
    }
    SBAR();  // all waves' tile-it DMAs visible
    // QK (S^T): m = k (2 subtiles of 16), n = q (2 subtiles), k-dim = d = 64
    for (int mt = 0; mt < 2; mt++) {
      const int rK = mt * 16 + l16;
      bf16x8 a0 = *(const bf16x8*)&Ksc[rK * 64 + ((quad ^ (rK & 7)) * 8)];
      bf16x8 a1 = *(const bf16x8*)&Ksc[rK * 64 + (((quad + 4) ^ (rK & 7)) * 8)];
      for (int nt = 0; nt < 2; nt++) {
        f32x4 s = MFMA16(a0, bQ[nt][0], fz);
        s = MFMA16(a1, bQ[nt][1], s);
        bf16x4 pk;
        pk[0] = (bf16_t)fexp2(s[0]);
        pk[1] = (bf16_t)fexp2(s[1]);
        pk[2] = (bf16_t)fexp2(s[2]);
        pk[3] = (bf16_t)fexp2(s[3]);
        // P row = q (wave*32+nt*16+l16), col = k (mt*16+quad*4), wave-private
        *(bf16x4*)&Ps[(wave * 32 + nt * 16 + l16) * 40 + mt * 16 + quad * 4] = pk;
      }
    }
    // PV: A-frag = Ps rows (q), k = 32 -> one b128 per q-subtile
    bf16x8 aP[2];
    for (int mt = 0; mt < 2; mt++)
      aP[mt] = *(const bf16x8*)&Ps[(wave * 32 + mt * 16 + l16) * 40 + quad * 8];
    for (int nd = 0; nd < 4; nd++) {
      const int rV = nd * 16 + l16;
      bf16x8 bv = *(const bf16x8*)&Vtsc[rV * 32 + ((quad ^ (rV & 3)) * 8)];
      acc[0][nd] = MFMA16(aP[0], bv, acc[0][nd]);
      acc[1][nd] = MFMA16(aP[1], bv, acc[1][nd]);
    }
    SBAR();  // all waves done reading Ks/Vts[cur] before next-iter restage
  }
  // epilogue: pool dead (last SBAR passed) -> alias as O[256][72]
  bf16_t* Ob = pool;
  for (int mt = 0; mt < 2; mt++)
    for (int nd = 0; nd < 4; nd++)
      for (int rg = 0; rg < 4; rg++)
        Ob[(wave * 32 + mt * 16 + quad * 4 + rg) * 72 + nd * 16 + l16] =
            (bf16_t)acc[mt][nd][rg];
  __syncthreads();
  const int row = wave * 32 + (lane >> 1), cc = (lane & 1) * 32;
  bf16_t* orow = oh + ((size_t)b * NQz + q0 + row) * 512 + h * 64 + cc;
  for (int c = 0; c < 4; c++)
    *(bf16x8*)(orow + c * 8) = *(const bf16x8*)&Ob[row * 72 + cc + c * 8];
}

// ---- LayerNorm over 512 cols, one wave per row, bf16 in.
template <int RES, int F32OUT>
__global__ __launch_bounds__(256) void ln_k(const bf16_t* __restrict__ x,
                                            const bf16_t* __restrict__ res,
                                            const float* __restrict__ g,
                                            const float* __restrict__ be,
                                            bf16_t* __restrict__ yb,
                                            float* __restrict__ yf) {
  const int wave = threadIdx.x >> 6, lane = threadIdx.x & 63;
  const size_t row = (size_t)blockIdx.x * 4 + wave;
  bf16x8 xv = *(const bf16x8*)(x + row * 512 + lane * 8);
  float xf[8];
  for (int i = 0; i < 8; i++) xf[i] = (float)xv[i];
  if (RES) {
    bf16x8 rv = *(const bf16x8*)(res + row * 512 + lane * 8);
    for (int i = 0; i < 8; i++) xf[i] += (float)rv[i];
  }
  float s = 0.f, sq = 0.f;
  for (int i = 0; i < 8; i++) { s += xf[i]; sq += xf[i] * xf[i]; }
  for (int off = 1; off < 64; off <<= 1) {
    s += __shfl_xor(s, off);
    sq += __shfl_xor(sq, off);
  }
  const float mu = s * (1.0f / 512.0f);
  const float var = sq * (1.0f / 512.0f) - mu * mu;
  const float rstd = rsqrtf(var + 1e-5f);
  float4 gv0 = *(const float4*)(g + lane * 8);
  float4 gv1 = *(const float4*)(g + lane * 8 + 4);
  float4 bv0 = *(const float4*)(be + lane * 8);
  float4 bv1 = *(const float4*)(be + lane * 8 + 4);
  float gg[8] = {gv0.x, gv0.y, gv0.z, gv0.w, gv1.x, gv1.y, gv1.z, gv1.w};
  float bb[8] = {bv0.x, bv0.y, bv0.z, bv0.w, bv1.x, bv1.y, bv1.z, bv1.w};
  float o[8];
  for (int i = 0; i < 8; i++) o[i] = (xf[i] - mu) * rstd * gg[i] + bb[i];
  if (F32OUT) {
    float4 o0 = {o[0], o[1], o[2], o[3]}, o1 = {o[4], o[5], o[6], o[7]};
    *(float4*)(yf + row * 512 + lane * 8) = o0;
    *(float4*)(yf + row * 512 + lane * 8 + 4) = o1;
  } else {
    bf16x8 ov;
    for (int i = 0; i < 8; i++) ov[i] = (bf16_t)o[i];
    *(bf16x8*)(yb + row * 512 + lane * 8) = ov;
  }
}

extern "C" void kernel_launch(void* const* d_in, const int* in_sizes, int n_in,
                              void* d_out, int out_size, void* d_ws, size_t ws_size,
                              hipStream_t stream) {
  (void)in_sizes; (void)n_in; (void)out_size; (void)ws_size;
  const float* Q   = (const float*)d_in[0];
  const float* K   = (const float*)d_in[1];
  const float* Wq  = (const float*)d_in[2];
  const float* bq  = (const float*)d_in[3];
  const float* Wk  = (const float*)d_in[4];
  const float* bk  = (const float*)d_in[5];
  const float* Wv  = (const float*)d_in[6];
  const float* bv  = (const float*)d_in[7];
  const float* Wo  = (const float*)d_in[8];
  const float* bo  = (const float*)d_in[9];
  const float* g0  = (const float*)d_in[10];
  const float* be0 = (const float*)d_in[11];
  const float* g1  = (const float*)d_in[12];
  const float* be1 = (const float*)d_in[13];
  float* outp = (float*)d_out;

  char* w = (char*)d_ws;
  bf16_t* Wt  = (bf16_t*)w;                     // 2 MB (4 x 512x512 bf16)
  bf16_t* qp  = (bf16_t*)(w + (2ull << 20));    // 32 MB (Q proj; residual source)
  bf16_t* kp  = (bf16_t*)(w + (34ull << 20));   // 32 MB (K proj, pre-scaled by SCALE*log2e)
  bf16_t* vp  = (bf16_t*)(w + (66ull << 20));   // 32 MB (V proj, dead after stats)
  bf16_t* Vt  = (bf16_t*)(w + (98ull << 20));   // 32 MB (V'/l transposed [hb][64][1024])
  bf16_t* ohb = (bf16_t*)(w + (130ull << 20));  // 32 MB (attn out, no resid)
  bf16_t* x0b = vp;                             // reuse: LN0 out
  bf16_t* oh2 = kp;                             // reuse: out-proj+relu+resid

  transpose_w<<<dim3(16, 16, 4), dim3(32, 8), 0, stream>>>(Wq, Wk, Wv, Wo, Wt);
  gemm_f32a<0><<<dim3(256, 4), 256, 0, stream>>>(Q, Wt, bq, nullptr, 1.0f, qp, nullptr);
  // fold log2(e) into K so attn kernels use native v_exp_f32 (exp2)
  gemm_f32a<1><<<dim3(256, 8), 256, 0, stream>>>(K, Wt + (1 << 18), bk, bv,
                                                 SCALE * 1.4426950408889634f, kp, vp);
  attn_stats<<<2048, 256, 0, stream>>>(qp, kp, vp, Vt);
  attn_out<<<1024, 512, 0, stream>>>(qp, kp, Vt, ohb);
  ln_k<1, 0><<<8192, 256, 0, stream>>>(ohb, qp, g0, be0, x0b, nullptr);
  gemm_bf16a<<<dim3(256, 4), 256, 0, stream>>>(x0b, Wt + 3 * (1 << 18), bo, oh2);
  ln_k<0, 1><<<8192, 256, 0, stream>>>(oh2, nullptr, g1, be1, nullptr, outp);
}